// Round 16
// baseline (131.460 us; speedup 1.0000x reference)
//
#include <hip/hip_runtime.h>

// VQ-VAE vector quantizer. N=131072 rows (32*64*64), D=64, K=512.
// X: NCHW f32 (32,64,64,64); W: (512,64) f32.
// out: [0]=loss, [1..8388609)=quantized NCHW, [8388609]=perplexity,
//      [8388610..)=one-hot encodings [131072][512].
#define BHW 262144
#define OUT_Q_OFF 1
#define OUT_P_OFF 8388609
#define OUT_E_OFF 8388610

// ws layout (4-byte words):
// [0..256)      loss partial slots (f32)   -- memset 0
// [768..1280)   wsq = ||e_k||^2 (f32)
// [1280..17664) bf16 codebook B-fragments for 32x32x16, PRE-SCALED by -2:
//               [tt=16][ks=4][lane=64] x 8 bf16 (code n = tt*32+(l&31), dims
//               d = ks*16+(l>>5)*8+e)
// [17664..148736) per-row argmin indices (i32)
#define IDX_W 17664

typedef __attribute__((ext_vector_type(8)))  short short8;
typedef __attribute__((ext_vector_type(16))) float f32x16;
typedef __attribute__((ext_vector_type(2)))  float f32x2;

__device__ __forceinline__ unsigned short f2bf(float f) {
    union { float f; unsigned u; } c; c.f = f;
    unsigned r = (c.u + 0x7FFFu + ((c.u >> 16) & 1u)) >> 16;  // RNE
    return (unsigned short)r;
}

__global__ __launch_bounds__(512) void vq_init(const float* __restrict__ W, float* __restrict__ ws) {
    const int tid = blockIdx.x * 512 + threadIdx.x;
    if (tid < 512) {
        const float4* W4 = (const float4*)W;
        float s = 0.f;
#pragma unroll
        for (int i = 0; i < 16; ++i) {
            float4 v = W4[tid * 16 + i];
            s = fmaf(v.x, v.x, s); s = fmaf(v.y, v.y, s);
            s = fmaf(v.z, v.z, s); s = fmaf(v.w, v.w, s);
        }
        ws[768 + tid] = s;
    } else {
        // 32x32x16 B-fragment pre-swizzle (scaled by -2): c -> (tt, ks, lane)
        const int c  = tid - 512;            // 0..4095
        const int l  = c & 63;
        const int ks = (c >> 6) & 3;
        const int tt = c >> 8;               // 0..15
        const int n  = tt * 32 + (l & 31);
        const int d0 = ks * 16 + (l >> 5) * 8;
        const float* src = W + n * 64 + d0;
        unsigned h0 = f2bf(-2.f * src[0]) | ((unsigned)f2bf(-2.f * src[1]) << 16);
        unsigned h1 = f2bf(-2.f * src[2]) | ((unsigned)f2bf(-2.f * src[3]) << 16);
        unsigned h2 = f2bf(-2.f * src[4]) | ((unsigned)f2bf(-2.f * src[5]) << 16);
        unsigned h3 = f2bf(-2.f * src[6]) | ((unsigned)f2bf(-2.f * src[7]) << 16);
        uint4* dst = (uint4*)(ws + 1280);
        dst[c] = make_uint4(h0, h1, h2, h3);
    }
}

// vq_main: 1 wave per block, 32 rows per wave via ONE 32x32 MFMA tile chain.
// 16 scan iterations (vs 32), 4 chained 32x32x16 MFMAs per iteration, 16
// independent compares. A row = l&31, k-slot = (l>>5)*8+e (same convention as
// B -> permutation cancels). C/D: col=l&31, row=(r&3)+8*(r>>2)+4*(l>>5) (m74/
// m101-verified). No LDS, no barriers.
__global__ __launch_bounds__(64) void vq_main(const float* __restrict__ X,
                                              const float* __restrict__ W,
                                              float* __restrict__ out,
                                              float* __restrict__ ws) {
    const int l  = threadIdx.x;          // 0..63
    const int cl = l & 31;               // A-row / B-col index
    const int hi = l >> 5;
    const int rowbase = blockIdx.x * 32; // 32 consecutive rows, same (b,h)
    const int b  = rowbase >> 12;
    const int h  = (rowbase >> 6) & 63;
    const int w0 = rowbase & 63;         // 0 or 32
    const int myw = w0 + cl;             // this lane's row (w)

    // ---- this lane's x: row myw, dims ks*16 + hi*8 + e (32 of 64 dims;
    //      partner lane l^32 holds the other 32) ----
    const float* xr = X + (size_t)b * BHW + (size_t)h * 64 + myw;
    float xf[32];
#pragma unroll
    for (int ks = 0; ks < 4; ++ks)
#pragma unroll
        for (int e = 0; e < 8; ++e)
            xf[ks * 8 + e] = xr[(size_t)(ks * 16 + hi * 8 + e) * 4096];
    short8 a0, a1, a2, a3;
#pragma unroll
    for (int e = 0; e < 8; ++e) {
        a0[e] = (short)f2bf(xf[e]);
        a1[e] = (short)f2bf(xf[8 + e]);
        a2[e] = (short)f2bf(xf[16 + e]);
        a3[e] = (short)f2bf(xf[24 + e]);
    }

    // ---- scan 512 codes in 16 tiles of 32 ----
    const short8* __restrict__ B8  = (const short8*)(ws + 1280);
    const float*  __restrict__ wsq = ws + 768;
    float bS[16]; int bK[16];
#pragma unroll
    for (int r = 0; r < 16; ++r) { bS[r] = 3.4e38f; bK[r] = 0; }

#pragma unroll 2
    for (int tt = 0; tt < 16; ++tt) {
        short8 f0 = B8[(tt * 4 + 0) * 64 + l];
        short8 f1 = B8[(tt * 4 + 1) * 64 + l];
        short8 f2 = B8[(tt * 4 + 2) * 64 + l];
        short8 f3 = B8[(tt * 4 + 3) * 64 + l];
        const float wq = wsq[tt * 32 + cl];  // this lane's code column
        const int   n  = tt * 32 + cl;
        f32x16 acc;
#pragma unroll
        for (int r = 0; r < 16; ++r) acc[r] = wq;
        acc = __builtin_amdgcn_mfma_f32_32x32x16_bf16(a0, f0, acc, 0, 0, 0);
        acc = __builtin_amdgcn_mfma_f32_32x32x16_bf16(a1, f1, acc, 0, 0, 0);
        acc = __builtin_amdgcn_mfma_f32_32x32x16_bf16(a2, f2, acc, 0, 0, 0);
        acc = __builtin_amdgcn_mfma_f32_32x32x16_bf16(a3, f3, acc, 0, 0, 0);
#pragma unroll
        for (int r = 0; r < 16; ++r) {
            if (acc[r] < bS[r]) { bS[r] = acc[r]; bK[r] = n; }
        }
    }

    // ---- min-reduce across the 32 code-lanes of each half (lowest-n tiebreak);
    //      half hi owns rows (r&3)+8*(r>>2)+4*hi ----
#pragma unroll
    for (int r = 0; r < 16; ++r) {
#pragma unroll
        for (int mask = 1; mask <= 16; mask <<= 1) {
            float os = __shfl_xor(bS[r], mask);
            int   ok = __shfl_xor(bK[r], mask);
            if (os < bS[r] || (os == bS[r] && ok < bK[r])) { bS[r] = os; bK[r] = ok; }
        }
    }

    // ---- broadcast per-row bests; inline one-hot writes; idx capture ----
    int rowBk = 0;   // best for this lane's own row (cl)
    int myBk  = 0;   // best for row l (lanes 0..31)
    f32x2* encB = (f32x2*)(out + OUT_E_OFF);
#pragma unroll
    for (int m = 0; m < 32; ++m) {
        const int rm   = (m & 3) + 4 * (m >> 3);     // reg holding row m
        const int srcl = ((m >> 2) & 1) * 32;        // in half hi=(m>>2)&1
        const int bkm  = __shfl(bK[rm], srcl);
        if (cl == m) rowBk = bkm;
        if (l == m)  myBk  = bkm;
        f32x2* erow = encB + (size_t)(rowbase + m) * 256;
#pragma unroll
        for (int cc = 0; cc < 4; ++cc) {
            const int p = cc * 64 + l;
            f32x2 v;
            v.x = (bkm == 2 * p)     ? 1.f : 0.f;
            v.y = (bkm == 2 * p + 1) ? 1.f : 0.f;
            erow[p] = v;
        }
    }
    if (l < 32) ((int*)ws)[IDX_W + rowbase + l] = myBk;

    // ---- quantized_st + loss (x register-resident; W rows L2-hot) ----
    const float4* W4 = (const float4*)W;
    float qv[32];
#pragma unroll
    for (int ks = 0; ks < 4; ++ks) {
        float4 qa = W4[rowBk * 16 + ks * 4 + hi * 2];
        float4 qb = W4[rowBk * 16 + ks * 4 + hi * 2 + 1];
        qv[ks * 8 + 0] = qa.x; qv[ks * 8 + 1] = qa.y;
        qv[ks * 8 + 2] = qa.z; qv[ks * 8 + 3] = qa.w;
        qv[ks * 8 + 4] = qb.x; qv[ks * 8 + 5] = qb.y;
        qv[ks * 8 + 6] = qb.z; qv[ks * 8 + 7] = qb.w;
    }
    float lsum = 0.f;
    float* op = out + OUT_Q_OFF + (size_t)b * BHW + (size_t)h * 64 + myw;
#pragma unroll
    for (int ks = 0; ks < 4; ++ks)
#pragma unroll
        for (int e = 0; e < 8; ++e) {
            float d = qv[ks * 8 + e] - xf[ks * 8 + e];
            lsum = fmaf(d, d, lsum);
            op[(size_t)(ks * 16 + hi * 8 + e) * 4096] = xf[ks * 8 + e] + d;
        }

    // ---- loss wave-reduce; spread atomics over 256 slots ----
#pragma unroll
    for (int off = 32; off >= 1; off >>= 1) lsum += __shfl_down(lsum, off);
    if (l == 0) atomicAdd(ws + (blockIdx.x & 255), lsum);
}

// vq_fin: single block. LDS histogram of 131072 indices, then finalize.
__global__ __launch_bounds__(512) void vq_fin(const float* __restrict__ ws, float* __restrict__ out) {
    __shared__ unsigned hist[512];
    __shared__ float redP[8], redL[8];
    const int t = threadIdx.x;
    hist[t] = 0u;
    __syncthreads();
    const uint4* __restrict__ idx4 = (const uint4*)((const int*)ws + IDX_W);
#pragma unroll 4
    for (int i = 0; i < 64; ++i) {
        uint4 v = idx4[i * 512 + t];
        atomicAdd(&hist[v.x], 1u);
        atomicAdd(&hist[v.y], 1u);
        atomicAdd(&hist[v.z], 1u);
        atomicAdd(&hist[v.w], 1u);
    }
    __syncthreads();
    float p = (float)hist[t] * (1.0f / 131072.0f);
    float s = p * logf(p + 1e-10f);
    float lp = (t < 256) ? ws[t] : 0.f;
#pragma unroll
    for (int off = 32; off >= 1; off >>= 1) {
        s  += __shfl_down(s, off);
        lp += __shfl_down(lp, off);
    }
    if ((t & 63) == 0) { redP[t >> 6] = s; redL[t >> 6] = lp; }
    __syncthreads();
    if (t == 0) {
        float tp = 0.f, tl = 0.f;
#pragma unroll
        for (int i = 0; i < 8; ++i) { tp += redP[i]; tl += redL[i]; }
        out[OUT_P_OFF] = expf(-tp);
        out[0] = tl * (1.25f / 8388608.0f);
    }
}

extern "C" void kernel_launch(void* const* d_in, const int* in_sizes, int n_in,
                              void* d_out, int out_size, void* d_ws, size_t ws_size,
                              hipStream_t stream) {
    const float* X = (const float*)d_in[0];
    const float* W = (const float*)d_in[1];
    float* out = (float*)d_out;
    float* ws  = (float*)d_ws;

    (void)hipMemsetAsync(d_ws, 0, 256 * sizeof(float), stream);   // loss slots
    vq_init<<<9, 512, 0, stream>>>(W, ws);
    vq_main<<<4096, 64, 0, stream>>>(X, W, out, ws);
    vq_fin<<<1, 512, 0, stream>>>(ws, out);
}

// Round 17
// 108.759 us; speedup vs baseline: 1.2087x; 1.2087x over previous
//
#include <hip/hip_runtime.h>

// VQ-VAE vector quantizer. N=131072 rows (32*64*64), D=64, K=512.
// X: NCHW f32 (32,64,64,64); W: (512,64) f32.
// out: [0]=loss, [1..8388609)=quantized NCHW, [8388609]=perplexity,
//      [8388610..)=one-hot encodings [131072][512].
#define BHW 262144
#define OUT_Q_OFF 1
#define OUT_P_OFF 8388609
#define OUT_E_OFF 8388610

// ws layout (4-byte words):
// [0..256)      loss partial slots (f32)   -- memset 0
// [768..1280)   wsq = ||e_k||^2 (f32)
// [1280..17664) bf16 codebook B-fragments, PRE-SCALED by -2: [tn=32][j=2][lane=64] x 8
// [17664..148736) per-row argmin indices (i32)
#define IDX_W 17664

typedef __attribute__((ext_vector_type(8))) short short8;
typedef __attribute__((ext_vector_type(4))) float f32x4;
typedef __attribute__((ext_vector_type(2))) float f32x2;

__device__ __forceinline__ unsigned short f2bf(float f) {
    union { float f; unsigned u; } c; c.f = f;
    unsigned r = (c.u + 0x7FFFu + ((c.u >> 16) & 1u)) >> 16;  // RNE
    return (unsigned short)r;
}

__global__ __launch_bounds__(512) void vq_init(const float* __restrict__ W, float* __restrict__ ws) {
    const int tid = blockIdx.x * 512 + threadIdx.x;
    if (tid < 512) {
        const float4* W4 = (const float4*)W;
        float s = 0.f;
#pragma unroll
        for (int i = 0; i < 16; ++i) {
            float4 v = W4[tid * 16 + i];
            s = fmaf(v.x, v.x, s); s = fmaf(v.y, v.y, s);
            s = fmaf(v.z, v.z, s); s = fmaf(v.w, v.w, s);
        }
        ws[768 + tid] = s;
    } else {
        const int c  = tid - 512;            // 0..4095
        const int l  = c & 63;
        const int j  = (c >> 6) & 1;
        const int tn = c >> 7;
        const int n  = tn * 16 + (l & 15);
        const int k0 = j * 32 + ((l >> 4) & 3) * 8;
        const float* src = W + n * 64 + k0;
        unsigned h0 = f2bf(-2.f * src[0]) | ((unsigned)f2bf(-2.f * src[1]) << 16);
        unsigned h1 = f2bf(-2.f * src[2]) | ((unsigned)f2bf(-2.f * src[3]) << 16);
        unsigned h2 = f2bf(-2.f * src[4]) | ((unsigned)f2bf(-2.f * src[5]) << 16);
        unsigned h3 = f2bf(-2.f * src[6]) | ((unsigned)f2bf(-2.f * src[7]) << 16);
        uint4* dst = (uint4*)(ws + 1280);
        dst[c] = make_uint4(h0, h1, h2, h3);
    }
}

// One lane's full tile pipeline stage: X loads for tile (rowbase), scan,
// epilogue. Structured so tile t+1's X loads are issued BEFORE tile t's scan.
__device__ __forceinline__ void load_x(const float* __restrict__ X, int rowbase,
                                       int nlow, int kg, float xf[16]) {
    const int b  = rowbase >> 12;
    const int h  = (rowbase >> 6) & 63;
    const int w0 = rowbase & 63;
    const float* xr = X + (size_t)b * BHW + (size_t)h * 64 + (w0 + nlow);
#pragma unroll
    for (int e = 0; e < 8; ++e) xf[e]     = xr[(size_t)(kg * 8 + e) * 4096];
#pragma unroll
    for (int e = 0; e < 8; ++e) xf[8 + e] = xr[(size_t)(32 + kg * 8 + e) * 4096];
}

__device__ __forceinline__ float do_tile(const float* __restrict__ W,
                                         float* __restrict__ out,
                                         float* __restrict__ ws,
                                         int rowbase, int l, int nlow, int kg,
                                         const float xf[16]) {
    const int b  = rowbase >> 12;
    const int h  = (rowbase >> 6) & 63;
    const int w0 = rowbase & 63;

    short8 a0, a1;
#pragma unroll
    for (int e = 0; e < 8; ++e) { a0[e] = (short)f2bf(xf[e]); a1[e] = (short)f2bf(xf[8 + e]); }

    const short8* __restrict__ B8  = (const short8*)(ws + 1280);
    const float*  __restrict__ wsq = ws + 768;
    float bS[4]; int bK[4];
#pragma unroll
    for (int r = 0; r < 4; ++r) { bS[r] = 3.4e38f; bK[r] = 0; }

#pragma unroll 4
    for (int tn = 0; tn < 32; ++tn) {
        short8 f0 = B8[tn * 128 + l];
        short8 f1 = B8[tn * 128 + 64 + l];
        const float wq = wsq[tn * 16 + nlow];
        f32x4 acc = {wq, wq, wq, wq};
        acc = __builtin_amdgcn_mfma_f32_16x16x32_bf16(a0, f0, acc, 0, 0, 0);
        acc = __builtin_amdgcn_mfma_f32_16x16x32_bf16(a1, f1, acc, 0, 0, 0);
        const int n = tn * 16 + nlow;
#pragma unroll
        for (int r = 0; r < 4; ++r) {
            if (acc[r] < bS[r]) { bS[r] = acc[r]; bK[r] = n; }
        }
    }
#pragma unroll
    for (int r = 0; r < 4; ++r) {
#pragma unroll
        for (int mask = 1; mask <= 8; mask <<= 1) {
            float os = __shfl_xor(bS[r], mask);
            int   ok = __shfl_xor(bK[r], mask);
            if (os < bS[r] || (os == bS[r] && ok < bK[r])) { bS[r] = os; bK[r] = ok; }
        }
    }

    // own-row best (row nlow lives in group nlow>>2, reg nlow&3)
    const int src = (nlow >> 2) * 16;
    const int sel = nlow & 3;
    int g0 = __shfl(bK[0], src), g1 = __shfl(bK[1], src);
    int g2 = __shfl(bK[2], src), g3 = __shfl(bK[3], src);
    const int rowBk = sel == 0 ? g0 : sel == 1 ? g1 : sel == 2 ? g2 : g3;

    // W gather issued before the store bursts
    const float4* W4 = (const float4*)W;
    float4 q0 = W4[rowBk * 16 + kg * 2];
    float4 q1 = W4[rowBk * 16 + kg * 2 + 1];
    float4 q2 = W4[rowBk * 16 + 8 + kg * 2];
    float4 q3 = W4[rowBk * 16 + 8 + kg * 2 + 1];

    if (l < 16) ((int*)ws)[IDX_W + rowbase + l] = rowBk;

    // one-hot encodings (coalesced f32x2)
    f32x2* encB = (f32x2*)(out + OUT_E_OFF);
#pragma unroll
    for (int m = 0; m < 16; ++m) {
        const int bkm = __shfl(bK[m & 3], (m >> 2) * 16);
        f32x2* erow = encB + (size_t)(rowbase + m) * 256;
#pragma unroll
        for (int c = 0; c < 4; ++c) {
            const int p = c * 64 + l;
            f32x2 v;
            v.x = (bkm == 2 * p)     ? 1.f : 0.f;
            v.y = (bkm == 2 * p + 1) ? 1.f : 0.f;
            erow[p] = v;
        }
    }

    // quantized_st + loss partial
    float qv[16] = {q0.x, q0.y, q0.z, q0.w, q1.x, q1.y, q1.z, q1.w,
                    q2.x, q2.y, q2.z, q2.w, q3.x, q3.y, q3.z, q3.w};
    float lsum = 0.f;
    float* op = out + OUT_Q_OFF + (size_t)b * BHW + (size_t)h * 64 + (w0 + nlow);
#pragma unroll
    for (int e = 0; e < 8; ++e) {
        float d0 = qv[e] - xf[e];
        lsum = fmaf(d0, d0, lsum);
        op[(size_t)(kg * 8 + e) * 4096] = xf[e] + d0;
        float d1 = qv[8 + e] - xf[8 + e];
        lsum = fmaf(d1, d1, lsum);
        op[(size_t)(32 + kg * 8 + e) * 4096] = xf[8 + e] + d1;
    }
    return lsum;
}

// vq_main: 4 independent waves/block (no LDS, no barriers). Each wave owns TWO
// consecutive 16-row tiles, software-pipelined: tile1's X loads are issued
// BEFORE tile0's scan, so the next chain's cold-head latency hides under the
// current chain's compute. Loss accumulated in-register, one atomic per wave.
__global__ __launch_bounds__(256, 4) void vq_main(const float* __restrict__ X,
                                                  const float* __restrict__ W,
                                                  float* __restrict__ out,
                                                  float* __restrict__ ws) {
    const int t    = threadIdx.x;
    const int l    = t & 63;
    const int wv   = t >> 6;
    const int nlow = l & 15;
    const int kg   = l >> 4;
    const int wid  = blockIdx.x * 4 + wv;    // 0..4095
    const int rb0  = wid * 32;               // tile 0 rows
    const int rb1  = rb0 + 16;               // tile 1 rows

    float xf0[16], xf1[16];
    load_x(X, rb0, nlow, kg, xf0);           // tile0 head
    load_x(X, rb1, nlow, kg, xf1);           // tile1 head: in flight during tile0 scan
    float lsum = do_tile(W, out, ws, rb0, l, nlow, kg, xf0);
    lsum     += do_tile(W, out, ws, rb1, l, nlow, kg, xf1);

#pragma unroll
    for (int off = 32; off >= 1; off >>= 1) lsum += __shfl_down(lsum, off);
    if (l == 0) atomicAdd(ws + (wid & 255), lsum);
}

// vq_fin: single block. LDS histogram of 131072 indices, then finalize.
__global__ __launch_bounds__(512) void vq_fin(const float* __restrict__ ws, float* __restrict__ out) {
    __shared__ unsigned hist[512];
    __shared__ float redP[8], redL[8];
    const int t = threadIdx.x;
    hist[t] = 0u;
    __syncthreads();
    const uint4* __restrict__ idx4 = (const uint4*)((const int*)ws + IDX_W);
#pragma unroll 4
    for (int i = 0; i < 64; ++i) {
        uint4 v = idx4[i * 512 + t];
        atomicAdd(&hist[v.x], 1u);
        atomicAdd(&hist[v.y], 1u);
        atomicAdd(&hist[v.z], 1u);
        atomicAdd(&hist[v.w], 1u);
    }
    __syncthreads();
    float p = (float)hist[t] * (1.0f / 131072.0f);
    float s = p * logf(p + 1e-10f);
    float lp = (t < 256) ? ws[t] : 0.f;
#pragma unroll
    for (int off = 32; off >= 1; off >>= 1) {
        s  += __shfl_down(s, off);
        lp += __shfl_down(lp, off);
    }
    if ((t & 63) == 0) { redP[t >> 6] = s; redL[t >> 6] = lp; }
    __syncthreads();
    if (t == 0) {
        float tp = 0.f, tl = 0.f;
#pragma unroll
        for (int i = 0; i < 8; ++i) { tp += redP[i]; tl += redL[i]; }
        out[OUT_P_OFF] = expf(-tp);
        out[0] = tl * (1.25f / 8388608.0f);
    }
}

extern "C" void kernel_launch(void* const* d_in, const int* in_sizes, int n_in,
                              void* d_out, int out_size, void* d_ws, size_t ws_size,
                              hipStream_t stream) {
    const float* X = (const float*)d_in[0];
    const float* W = (const float*)d_in[1];
    float* out = (float*)d_out;
    float* ws  = (float*)d_ws;

    (void)hipMemsetAsync(d_ws, 0, 256 * sizeof(float), stream);   // loss slots
    vq_init<<<9, 512, 0, stream>>>(W, ws);
    vq_main<<<1024, 256, 0, stream>>>(X, W, out, ws);
    vq_fin<<<1, 512, 0, stream>>>(ws, out);
}